// Round 1
// baseline (1066.791 us; speedup 1.0000x reference)
//
#include <hip/hip_runtime.h>
#include <hip/hip_bf16.h>
#include <stdint.h>
#include <stddef.h>

#define LIN   4096
#define TOUT  4097            // 4096 + 2*28 - 56 + 1
#define NBATCH 32
#define TPAD  4416            // 28 + 4096 + 28 = 4152, padded up for tile overread
#define MT    128             // o-tile
#define NT    256             // t-tile
#define XROWS (NT + 56)       // 312 staged x rows per c-chunk

typedef __attribute__((ext_vector_type(8)))  short short8;
typedef __attribute__((ext_vector_type(16))) float float16;

#define XT_ELEMS ((size_t)NBATCH * TPAD * 256)
#define XT_BYTES (XT_ELEMS * 2)
#define KD_ELEMS ((size_t)56 * 4 * 256 * 64)

// ---------------- prep 1: pad + transpose + bf16:  xT[b][tp][c] ----------------
__global__ __launch_bounds__(256) void xpose_kernel(const float* __restrict__ x,
                                                    __hip_bfloat16* __restrict__ xT) {
  const int t0  = blockIdx.x * 64;
  const int b   = blockIdx.y;
  const int tid = threadIdx.x;
  __shared__ __hip_bfloat16 tile[64 * 66];
  for (int c0 = 0; c0 < 256; c0 += 64) {
#pragma unroll
    for (int j = 0; j < 16; ++j) {
      int f = j * 256 + tid;
      int c_l = f >> 6, t_l = f & 63;            // lanes consecutive in t -> coalesced read
      float v = x[((size_t)(b * 256 + c0 + c_l)) * LIN + t0 + t_l];
      tile[t_l * 66 + c_l] = __float2bfloat16(v);
    }
    __syncthreads();
#pragma unroll
    for (int j = 0; j < 16; ++j) {
      int f = j * 256 + tid;
      int t_l = f >> 6, c_l = f & 63;            // lanes consecutive in c -> coalesced write
      xT[((size_t)(b * TPAD + 28 + t0 + t_l)) * 256 + c0 + c_l] = tile[t_l * 66 + c_l];
    }
    __syncthreads();
  }
}

// ---------------- prep 2: dense bf16 kernel  Kd[l][cc][o][c64] ----------------
__global__ __launch_bounds__(256) void build_kd(const float* __restrict__ w,
                                                const float* __restrict__ P,
                                                __hip_bfloat16* __restrict__ Kd) {
  const int o = blockIdx.x;
  const int c = threadIdx.x;
  __shared__ float accs[256 * 56];
  float* a = &accs[c * 56];
  for (int l = 0; l < 56; ++l) a[l] = 0.0f;
  const int base = (o * 256 + c) * 7;
#pragma unroll
  for (int k = 0; k < 7; ++k) {
    float wv  = w[base + k];
    float pos = P[base + k] + 28.0f;
    pos = fminf(fmaxf(pos, 0.0f), 55.0f);        // clamp border (matches jnp.clip)
    float lo  = floorf(pos);
    float fr  = pos - lo;
    int li = (int)lo;
    int hi = li + 1; if (hi > 55) hi = 55;
    a[li] += wv * (1.0f - fr);
    a[hi] += wv * fr;
  }
  for (int l = 0; l < 56; ++l) {
    size_t idx = (((size_t)(l * 4 + (c >> 6)) * 256 + o) << 6) + (c & 63);
    Kd[idx] = __float2bfloat16(a[l]);
  }
}

// ---------------- main: implicit-GEMM conv via 32x32x16 bf16 MFMA ----------------
// block: 256 thr = 4 waves; out tile 128(o) x 256(t); wave tile 64x128 (2x4 of 32x32)
// K-loop: cc-chunk of 64 c (x tile staged once, reused over all 56 l),
//         per-l 16KB A slab double-buffered in LDS with global->reg prefetch.
// LDS rows are 128B (64 bf16); 16B units XOR-swizzled by (row&7) so fragment
// ds_read_b128 of 32 consecutive rows covers all 32 banks per 8 rows.
__global__ __launch_bounds__(256, 2) void conv_mfma(const __hip_bfloat16* __restrict__ xT,
                                                    const __hip_bfloat16* __restrict__ Kd,
                                                    const float* __restrict__ bias,
                                                    float* __restrict__ out) {
  extern __shared__ char smem[];
  __hip_bfloat16* xs  = (__hip_bfloat16*)smem;                    // 312*64*2 = 39936 B
  __hip_bfloat16* As0 = (__hip_bfloat16*)(smem + 39936);          // 16384 B
  __hip_bfloat16* As1 = (__hip_bfloat16*)(smem + 39936 + 16384);  // 16384 B

  const int tid  = threadIdx.x;
  const int o0   = blockIdx.x * MT;
  const int t0   = blockIdx.y * NT;
  const int b    = blockIdx.z;
  const int wid  = tid >> 6;
  const int lane = tid & 63;
  const int m_off = (wid & 1) * 64;
  const int n_off = (wid >> 1) * 128;
  const int laneN = lane & 31;
  const int half  = lane >> 5;

  float16 acc[2][4];
#pragma unroll
  for (int i = 0; i < 2; ++i)
#pragma unroll
    for (int j = 0; j < 4; ++j) acc[i][j] = (float16)(0.0f);

  for (int cc = 0; cc < 4; ++cc) {
    // ---- stage x tile [312 t][64 c], swizzled ----
    {
      const size_t gbase = ((size_t)(b * TPAD + t0)) * 256 + cc * 64;
#pragma unroll
      for (int j = 0; j < 10; ++j) {
        int f = j * 256 + tid;
        if (f < XROWS * 8) {
          int r = f >> 3, u = f & 7;
          int4 v = *(const int4*)(xT + gbase + (size_t)r * 256 + u * 8);
          *(int4*)((char*)xs + r * 128 + ((u ^ (r & 7)) << 4)) = v;
        }
      }
    }
    // ---- stage A slab for l=0 ----
    const size_t AbaseCC = ((size_t)(cc * 256 + o0)) << 6;   // + l*65536 elements per l
    int4 areg[4];
#pragma unroll
    for (int j = 0; j < 4; ++j)
      areg[j] = *(const int4*)(Kd + AbaseCC + (size_t)(j * 256 + tid) * 8);
#pragma unroll
    for (int j = 0; j < 4; ++j) {
      int f = j * 256 + tid; int r = f >> 3, u = f & 7;
      *(int4*)((char*)As0 + r * 128 + ((u ^ (r & 7)) << 4)) = areg[j];
    }
    __syncthreads();

    for (int l = 0; l < 56; ++l) {
      const __hip_bfloat16* Acur = (l & 1) ? As1 : As0;
      __hip_bfloat16* Anxt = (l & 1) ? As0 : As1;
      // prefetch next A slab into registers (overlaps MFMA below)
      if (l + 1 < 56) {
        const size_t nb = AbaseCC + (size_t)(l + 1) * 65536;
#pragma unroll
        for (int j = 0; j < 4; ++j)
          areg[j] = *(const int4*)(Kd + nb + (size_t)(j * 256 + tid) * 8);
      }
      // ---- compute: 4 ksteps of 16 over the 64-c chunk ----
#pragma unroll
      for (int kk = 0; kk < 4; ++kk) {
        const int u = (kk << 1) + half;        // 16B unit = (kk*16 + half*8)/8
        short8 afr[2], bfr[4];
#pragma unroll
        for (int i = 0; i < 2; ++i) {
          int row = m_off + i * 32 + laneN;
          afr[i] = *(const short8*)((const char*)Acur + row * 128 + ((u ^ (row & 7)) << 4));
        }
#pragma unroll
        for (int jn = 0; jn < 4; ++jn) {
          int row = n_off + jn * 32 + laneN + l;
          bfr[jn] = *(const short8*)((const char*)xs + row * 128 + ((u ^ (row & 7)) << 4));
        }
#pragma unroll
        for (int i = 0; i < 2; ++i)
#pragma unroll
          for (int jn = 0; jn < 4; ++jn)
            acc[i][jn] = __builtin_amdgcn_mfma_f32_32x32x16_bf16(afr[i], bfr[jn], acc[i][jn], 0, 0, 0);
      }
      // ---- write prefetched slab to the other buffer ----
      if (l + 1 < 56) {
#pragma unroll
        for (int j = 0; j < 4; ++j) {
          int f = j * 256 + tid; int r = f >> 3, u2 = f & 7;
          *(int4*)((char*)Anxt + r * 128 + ((u2 ^ (r & 7)) << 4)) = areg[j];
        }
      }
      __syncthreads();
    }
  }

  // ---- epilogue: C/D layout col=lane&31, row=(reg&3)+8*(reg>>2)+4*(lane>>5) ----
#pragma unroll
  for (int i = 0; i < 2; ++i) {
#pragma unroll
    for (int jn = 0; jn < 4; ++jn) {
      int t = t0 + n_off + jn * 32 + laneN;
      if (t < TOUT) {
#pragma unroll
        for (int r = 0; r < 16; ++r) {
          int row = (r & 3) + 8 * (r >> 2) + 4 * half;
          int o = o0 + m_off + i * 32 + row;
          out[((size_t)(b * 256 + o)) * TOUT + t] = acc[i][jn][r] + bias[o];
        }
      }
    }
  }
}

extern "C" void kernel_launch(void* const* d_in, const int* in_sizes, int n_in,
                              void* d_out, int out_size, void* d_ws, size_t ws_size,
                              hipStream_t stream) {
  const float* x    = (const float*)d_in[0];
  const float* w    = (const float*)d_in[1];
  const float* P    = (const float*)d_in[2];
  const float* bias = (const float*)d_in[3];
  float* out = (float*)d_out;

  __hip_bfloat16* xT = (__hip_bfloat16*)d_ws;
  __hip_bfloat16* Kd = (__hip_bfloat16*)((char*)d_ws + XT_BYTES);

  // zero the padded/overread regions of xT (interior overwritten by xpose_kernel)
  hipMemsetAsync(d_ws, 0, XT_BYTES, stream);

  xpose_kernel<<<dim3(LIN / 64, NBATCH), 256, 0, stream>>>(x, xT);
  build_kd<<<dim3(256), 256, 0, stream>>>(w, P, Kd);

  const int smem_bytes = 39936 + 2 * 16384;  // 72704
  static bool attr_set = false;  // host-side only; harmless under graph capture
  (void)attr_set;
  hipFuncSetAttribute((const void*)conv_mfma, hipFuncAttributeMaxDynamicSharedMemorySize,
                      smem_bytes);
  conv_mfma<<<dim3(256 / MT, (TOUT + NT - 1) / NT, NBATCH), 256, smem_bytes, stream>>>(
      xT, Kd, bias, out);
}